// Round 1
// baseline (1188.003 us; speedup 1.0000x reference)
//
#include <hip/hip_runtime.h>

// Problem: B=1024, T=128, LAT=128, HODE=128, HID=256, OUT=128, NC=2, H=64.
// d_out = xs [128,1024,128] f32  ++  lstm_out [1024,2] f32  (16779264 floats)
//
// Key structural facts used:
//  * RK4 chain is independent per batch row -> per-workgroup integration, no grid sync.
//  * nn.LSTM scans dim0=B with batch T+1=129, but only batch element 128 is read
//    (lstm_hs[:, -1, :]) -> single 1024-step LSTM chain with input y_final[t].
//  * l2h/h2o have no nonlinearity between them -> fuse into Wf[128][128].

typedef short s16x8 __attribute__((ext_vector_type(8)));
typedef float f32x4 __attribute__((ext_vector_type(4)));

#define MFMA16(a, b, c) __builtin_amdgcn_mfma_f32_16x16x32_bf16((a), (b), (c), 0, 0, 0)

__device__ __forceinline__ unsigned short f2bf(float x) {
  union { float f; unsigned u; } v; v.f = x;
  return (unsigned short)((v.u + 0x7FFFu + ((v.u >> 16) & 1u)) >> 16);  // RNE
}

__device__ __forceinline__ float tanhst(float x) {
  float e = __expf(-2.f * fabsf(x));
  float t = (1.f - e) / (1.f + e);
  return x >= 0.f ? t : -t;
}

// XOR-swizzled LDS byte offset for a [rows][128] bf16 tile (row stride 256B).
// G4: row-major D=128 bf16 tiles are 16/32-way bank conflicts; byte ^= (row&7)<<4 fixes.
__device__ __forceinline__ int swz(int row, int col2) {
  return row * 256 + (col2 ^ ((row & 7) << 4));
}

__device__ __forceinline__ void gemm_tile(const unsigned char* base,
                                          const int* aOff,
                                          const s16x8* wf0, const s16x8* wf1,
                                          f32x4& a0, f32x4& a1) {
#pragma unroll
  for (int ks = 0; ks < 4; ++ks) {
    s16x8 a = *(const s16x8*)(base + aOff[ks]);
    a0 = MFMA16(a, wf0[ks], a0);
    a1 = MFMA16(a, wf1[ks], a1);
  }
}

// ---------------------------------------------------------------------------
// Kernel 1: fused projection weight  Wf[o][k] = sum_h h2o[o][h]*l2h[h][k],
//           bfused[o] = sum_h h2o[o][h]*l2h_b[h] + h2o_b[o]
// ---------------------------------------------------------------------------
__global__ __launch_bounds__(128) void wf_kernel(
    const float* __restrict__ h2o, const float* __restrict__ l2h,
    const float* __restrict__ l2hb, const float* __restrict__ h2ob,
    unsigned short* __restrict__ wfo, float* __restrict__ bfo)
{
  const int o = (int)blockIdx.x, k = (int)threadIdx.x;
  float acc = 0.f;
  for (int h = 0; h < 256; ++h) acc = fmaf(h2o[o * 256 + h], l2h[h * 128 + k], acc);
  wfo[o * 128 + k] = f2bf(acc);
  __shared__ float red[128];
  red[k] = h2o[o * 256 + k] * l2hb[k] + h2o[o * 256 + 128 + k] * l2hb[128 + k];
  __syncthreads();
  for (int s = 64; s > 0; s >>= 1) {
    if (k < s) red[k] += red[k + s];
    __syncthreads();
  }
  if (k == 0) bfo[o] = red[0] + h2ob[o];
}

// ---------------------------------------------------------------------------
// Kernel 2: RK4 ODE integration. 64 blocks x 16 rows, 256 thr (4 waves).
// Weights W1,W2 live as MFMA B-fragments in registers (no LDS reads for B).
// f32 state y0/yacc in registers (C/D lane layout); bf16 stage input via LDS.
// Writes zs (bf16, [s][b][k]) and y_final (f32).
// ---------------------------------------------------------------------------
__global__ __launch_bounds__(256) void ode_kernel(
    const float* __restrict__ init, const float* __restrict__ ts,
    const float* __restrict__ w1, const float* __restrict__ b1,
    const float* __restrict__ w2, const float* __restrict__ b2,
    unsigned short* __restrict__ zbuf, float* __restrict__ yfin)
{
  __shared__ __align__(16) unsigned char sY[4096];  // 16 x 128 bf16, swizzled
  __shared__ __align__(16) unsigned char sH[4096];
  const int tid = (int)threadIdx.x;
  const int w = tid >> 6, lane = tid & 63;
  const int l15 = lane & 15, l4 = lane >> 4;
  const int rowbase = (int)blockIdx.x * 16;
  const int colbase = w * 32;  // wave owns cols [colbase, colbase+32)

  // --- B-fragments of W1, W2 into registers (layout: lane holds B[kb+(l>>4)*8+t][16ct+(l&15)])
  s16x8 w1f[2][4], w2f[2][4];
#pragma unroll
  for (int tc = 0; tc < 2; ++tc) {
    const int rj = colbase + 16 * tc + l15;
#pragma unroll
    for (int ks = 0; ks < 4; ++ks) {
      const int kb = ks * 32 + l4 * 8;
      s16x8 va, vb;
#pragma unroll
      for (int t = 0; t < 8; ++t) {
        va[t] = (short)f2bf(w1[rj * 128 + kb + t]);
        vb[t] = (short)f2bf(w2[rj * 128 + kb + t]);
      }
      w1f[tc][ks] = va; w2f[tc][ks] = vb;
    }
  }
  float b1v[2], b2v[2];
#pragma unroll
  for (int tc = 0; tc < 2; ++tc) {
    const int cc = colbase + 16 * tc + l15;
    b1v[tc] = b1[cc]; b2v[tc] = b2[cc];
  }

  // per-lane constant LDS offsets
  int aOff[4];
#pragma unroll
  for (int ks = 0; ks < 4; ++ks) aOff[ks] = swz(l15, (ks * 32 + l4 * 8) * 2);
  int cOff[2][4];
#pragma unroll
  for (int tc = 0; tc < 2; ++tc)
#pragma unroll
    for (int r = 0; r < 4; ++r)
      cOff[tc][r] = swz(l4 * 4 + r, (colbase + 16 * tc + l15) * 2);

  // f32 master state in C/D lane layout: row=(l>>4)*4+r, col=colbase+16tc+(l&15)
  float y0[2][4], yac[2][4];
#pragma unroll
  for (int tc = 0; tc < 2; ++tc)
#pragma unroll
    for (int r = 0; r < 4; ++r)
      y0[tc][r] = init[(rowbase + l4 * 4 + r) * 128 + colbase + 16 * tc + l15];

  {  // stage initial y into sY (A-layout) + export zs slice 0
    const int i = tid * 8;
    const int row = i >> 7, col = i & 127;
    union { unsigned short u[8]; s16x8 v; } p;
#pragma unroll
    for (int t = 0; t < 8; ++t) p.u[t] = f2bf(init[(rowbase + row) * 128 + col + t]);
    *(s16x8*)(sY + swz(row, col * 2)) = p.v;
    *(s16x8*)(zbuf + rowbase * 128 + i) = p.v;
  }
  __syncthreads();

  for (int s = 0; s < 127; ++s) {
    const float dt = ts[s + 1] - ts[s];
    const float c16 = dt * (1.f / 6.f), c13 = dt * (1.f / 3.f), ch = dt * 0.5f;
#pragma unroll
    for (int st = 0; st < 4; ++st) {
      // GEMM1: sY @ W1^T -> ELU -> sH
      f32x4 acc[2];
      const f32x4 fz = {0.f, 0.f, 0.f, 0.f};
      acc[0] = fz; acc[1] = fz;
      gemm_tile(sY, aOff, w1f[0], w1f[1], acc[0], acc[1]);
#pragma unroll
      for (int tc = 0; tc < 2; ++tc)
#pragma unroll
        for (int r = 0; r < 4; ++r) {
          float v = acc[tc][r] + b1v[tc];
          v = v > 0.f ? v : expm1f(v);  // ELU (alpha=1)
          *(unsigned short*)(sH + cOff[tc][r]) = f2bf(v);
        }
      __syncthreads();
      // GEMM2: sH @ W2^T -> k_st ; RK4 combine in registers
      f32x4 kc[2];
      kc[0] = fz; kc[1] = fz;
      gemm_tile(sH, aOff, w2f[0], w2f[1], kc[0], kc[1]);
#pragma unroll
      for (int tc = 0; tc < 2; ++tc)
#pragma unroll
        for (int r = 0; r < 4; ++r) {
          const float kv = kc[tc][r] + b2v[tc];
          float yn;
          if (st == 0)      { yac[tc][r] = fmaf(c16, kv, y0[tc][r]);  yn = fmaf(ch, kv, y0[tc][r]); }
          else if (st == 1) { yac[tc][r] = fmaf(c13, kv, yac[tc][r]); yn = fmaf(ch, kv, y0[tc][r]); }
          else if (st == 2) { yac[tc][r] = fmaf(c13, kv, yac[tc][r]); yn = fmaf(dt, kv, y0[tc][r]); }
          else              { y0[tc][r]  = fmaf(c16, kv, yac[tc][r]); yn = y0[tc][r]; }
          *(unsigned short*)(sY + cOff[tc][r]) = f2bf(yn);
        }
      __syncthreads();
    }
    {  // export zs slice s+1 (coalesced 16B per thread)
      const int i = tid * 8;
      const int row = i >> 7;
      const s16x8 v = *(const s16x8*)(sY + swz(row, (i & 127) * 2));
      *(s16x8*)(zbuf + (long)(s + 1) * 131072 + rowbase * 128 + i) = v;
    }
  }
#pragma unroll
  for (int tc = 0; tc < 2; ++tc)
#pragma unroll
    for (int r = 0; r < 4; ++r)
      yfin[(rowbase + l4 * 4 + r) * 128 + colbase + 16 * tc + l15] = y0[tc][r];
}

// ---------------------------------------------------------------------------
// Kernel 3: XW[t][g] = Wih[g] . yfin[t] + bih[g] + bhh[g]
// ---------------------------------------------------------------------------
__global__ __launch_bounds__(256) void xw_kernel(
    const float* __restrict__ yfin, const float* __restrict__ wih,
    const float* __restrict__ bih, const float* __restrict__ bhh,
    float* __restrict__ XW)
{
  const int t = (int)blockIdx.x, g = (int)threadIdx.x;
  __shared__ __align__(16) float ys[128];
  if (g < 128) ys[g] = yfin[t * 128 + g];
  __syncthreads();
  float a0 = 0.f, a1 = 0.f, a2 = 0.f, a3 = 0.f;
#pragma unroll 8
  for (int k = 0; k < 32; ++k) {
    float4 wv = *(const float4*)(wih + g * 128 + 4 * k);
    float4 yv = *(const float4*)(ys + 4 * k);
    a0 = fmaf(wv.x, yv.x, a0); a1 = fmaf(wv.y, yv.y, a1);
    a2 = fmaf(wv.z, yv.z, a2); a3 = fmaf(wv.w, yv.w, a3);
  }
  XW[t * 256 + g] = bih[g] + bhh[g] + ((a0 + a1) + (a2 + a3));
}

// ---------------------------------------------------------------------------
// Kernel 4: the single surviving LSTM chain (1024 sequential steps).
// 256 threads = 4 waves; wave q computes gate quarter q (i,f,g,o) -> wave-uniform
// nonlinearity branch. Whh rows in registers (64 VGPR/thread).
// ---------------------------------------------------------------------------
__global__ __launch_bounds__(256) void lstm_kernel(
    const float* __restrict__ XW, const float* __restrict__ whh,
    float* __restrict__ hsall)
{
  const int g = (int)threadIdx.x;
  float wr[64];
#pragma unroll
  for (int k = 0; k < 16; ++k) {
    float4 v = *(const float4*)(whh + g * 64 + 4 * k);
    wr[4 * k + 0] = v.x; wr[4 * k + 1] = v.y; wr[4 * k + 2] = v.z; wr[4 * k + 3] = v.w;
  }
  __shared__ __align__(16) float hs[64];
  __shared__ float gl[256];
  if (g < 64) hs[g] = 0.f;
  float c = 0.f;
  __syncthreads();
  float xw_cur = XW[g];
  for (int t = 0; t < 1024; ++t) {
    const float xw_next = (t < 1023) ? XW[(t + 1) * 256 + g] : 0.f;  // prefetch
    float a0 = 0.f, a1 = 0.f, a2 = 0.f, a3 = 0.f;
#pragma unroll
    for (int k = 0; k < 16; ++k) {
      float4 h = *(const float4*)(hs + 4 * k);
      a0 = fmaf(wr[4 * k + 0], h.x, a0); a1 = fmaf(wr[4 * k + 1], h.y, a1);
      a2 = fmaf(wr[4 * k + 2], h.z, a2); a3 = fmaf(wr[4 * k + 3], h.w, a3);
    }
    const float pre = xw_cur + ((a0 + a1) + (a2 + a3));
    float act;
    if ((g >> 6) == 2) act = tanhst(pre);               // g-gate wave: tanh
    else               act = 1.f / (1.f + __expf(-pre)); // i,f,o waves: sigmoid
    gl[g] = act;
    __syncthreads();
    if (g < 64) {
      const float ig = gl[g], fg = gl[64 + g], gg = gl[128 + g], og = gl[192 + g];
      c = fmaf(fg, c, ig * gg);
      const float h = og * tanhst(c);
      hs[g] = h;
      hsall[t * 64 + g] = h;
    }
    __syncthreads();
    xw_cur = xw_next;
  }
}

// ---------------------------------------------------------------------------
// Kernel 5: lstm_out[t][n] = fc2_w[n] . h_t + fc2_b[n]
// ---------------------------------------------------------------------------
__global__ __launch_bounds__(256) void fc2_kernel(
    const float* __restrict__ hsall, const float* __restrict__ fw,
    const float* __restrict__ fb, float* __restrict__ lout)
{
  const int idx = (int)blockIdx.x * 256 + (int)threadIdx.x;  // 0..2047
  const int t = idx >> 1, n = idx & 1;
  float acc = fb[n];
#pragma unroll 8
  for (int j = 0; j < 64; ++j) acc = fmaf(fw[n * 64 + j], hsall[t * 64 + j], acc);
  lout[t * 2 + n] = acc;
}

// ---------------------------------------------------------------------------
// Kernel 6: xs = zs @ Wf^T + bfused. LDS-free MFMA: Wf fragments in registers,
// A-fragments straight from global (bf16 zs). 2048 blocks x 64 rows.
// ---------------------------------------------------------------------------
__global__ __launch_bounds__(256) void proj_kernel(
    const unsigned short* __restrict__ zbuf, const unsigned short* __restrict__ wf,
    const float* __restrict__ bfv_, float* __restrict__ xs)
{
  const int tid = (int)threadIdx.x;
  const int w = tid >> 6, lane = tid & 63;
  const int l15 = lane & 15, l4 = lane >> 4;
  const int colbase = w * 32;
  const long rowbase = (long)blockIdx.x * 64;

  s16x8 wff[2][4];
#pragma unroll
  for (int tc = 0; tc < 2; ++tc) {
    const int rj = colbase + 16 * tc + l15;
#pragma unroll
    for (int ks = 0; ks < 4; ++ks)
      wff[tc][ks] = *(const s16x8*)(wf + rj * 128 + ks * 32 + l4 * 8);
  }
  const float bv0 = bfv_[colbase + l15], bv1 = bfv_[colbase + 16 + l15];

  const f32x4 fz = {0.f, 0.f, 0.f, 0.f};
  f32x4 acc[4][2];
#pragma unroll
  for (int rt = 0; rt < 4; ++rt) { acc[rt][0] = fz; acc[rt][1] = fz; }

#pragma unroll
  for (int rt = 0; rt < 4; ++rt) {
    const long rb = rowbase + rt * 16 + l15;
#pragma unroll
    for (int ks = 0; ks < 4; ++ks) {
      const s16x8 a = *(const s16x8*)(zbuf + rb * 128 + ks * 32 + l4 * 8);
      acc[rt][0] = MFMA16(a, wff[0][ks], acc[rt][0]);
      acc[rt][1] = MFMA16(a, wff[1][ks], acc[rt][1]);
    }
  }
#pragma unroll
  for (int rt = 0; rt < 4; ++rt)
#pragma unroll
    for (int r = 0; r < 4; ++r) {
      const long row = rowbase + rt * 16 + l4 * 4 + r;
      xs[row * 128 + colbase + l15]      = acc[rt][0][r] + bv0;
      xs[row * 128 + colbase + 16 + l15] = acc[rt][1][r] + bv1;
    }
}

// ---------------------------------------------------------------------------
extern "C" void kernel_launch(void* const* d_in, const int* in_sizes, int n_in,
                              void* d_out, int out_size, void* d_ws, size_t ws_size,
                              hipStream_t stream) {
  const float* init  = (const float*)d_in[0];
  const float* ts    = (const float*)d_in[1];
  const float* ode_w1 = (const float*)d_in[2];
  const float* ode_b1 = (const float*)d_in[3];
  const float* ode_w2 = (const float*)d_in[4];
  const float* ode_b2 = (const float*)d_in[5];
  const float* l2h_w = (const float*)d_in[6];
  const float* l2h_b = (const float*)d_in[7];
  const float* h2o_w = (const float*)d_in[8];
  const float* h2o_b = (const float*)d_in[9];
  const float* wih   = (const float*)d_in[10];
  const float* whh   = (const float*)d_in[11];
  const float* bih   = (const float*)d_in[12];
  const float* bhh   = (const float*)d_in[13];
  const float* fc2w  = (const float*)d_in[14];
  const float* fc2b  = (const float*)d_in[15];

  char* ws = (char*)d_ws;
  unsigned short* zbuf  = (unsigned short*)(ws);               // 33,554,432 B
  float* yfin           = (float*)(ws + 33554432);             //    524,288 B
  float* XW             = (float*)(ws + 34078720);             //  1,048,576 B
  float* hsall          = (float*)(ws + 35127296);             //    262,144 B
  unsigned short* wfbuf = (unsigned short*)(ws + 35389440);    //     32,768 B
  float* bfused         = (float*)(ws + 35422208);             //        512 B

  float* xs   = (float*)d_out;
  float* lout = xs + 16777216;

  wf_kernel<<<128, 128, 0, stream>>>(h2o_w, l2h_w, l2h_b, h2o_b, wfbuf, bfused);
  ode_kernel<<<64, 256, 0, stream>>>(init, ts, ode_w1, ode_b1, ode_w2, ode_b2, zbuf, yfin);
  xw_kernel<<<1024, 256, 0, stream>>>(yfin, wih, bih, bhh, XW);
  proj_kernel<<<2048, 256, 0, stream>>>(zbuf, wfbuf, bfused, xs);
  lstm_kernel<<<1, 256, 0, stream>>>(XW, whh, hsall);
  fc2_kernel<<<8, 256, 0, stream>>>(hsall, fc2w, fc2b, lout);
}

// Round 3
// 813.637 us; speedup vs baseline: 1.4601x; 1.4601x over previous
//
#include <hip/hip_runtime.h>

// B=1024, T=128, LAT=128, HODE=128, HID=256, OUT=128, NC=2, H=64.
// d_out = xs [128,1024,128] f32 ++ lstm_out [1024,2] f32.
//
// Structure: wf (fuse l2h*h2o) ; ode (per-block RK4 chains) ; xw (Wih.yfin, transposed out)
//            fused(proj blocks 0..2047 || lstm chain block 2048) ; fc2.

typedef short s16x8 __attribute__((ext_vector_type(8)));
typedef float f32x4 __attribute__((ext_vector_type(4)));
typedef float f32x2 __attribute__((ext_vector_type(2)));

#define MFMA16(a, b, c) __builtin_amdgcn_mfma_f32_16x16x32_bf16((a), (b), (c), 0, 0, 0)

__device__ __forceinline__ unsigned short f2bf(float x) {
  union { float f; unsigned u; } v; v.f = x;
  return (unsigned short)((v.u + 0x7FFFu + ((v.u >> 16) & 1u)) >> 16);  // RNE
}

// XOR-swizzled LDS byte offset for a [rows][128] bf16 tile (row stride 256B).
__device__ __forceinline__ int swz(int row, int col2) {
  return row * 256 + (col2 ^ ((row & 7) << 4));
}

__device__ __forceinline__ void gemm_tile(const unsigned char* base,
                                          const int* aOff,
                                          const s16x8* wf0, const s16x8* wf1,
                                          f32x4& a0, f32x4& a1) {
#pragma unroll
  for (int ks = 0; ks < 4; ++ks) {
    s16x8 a = *(const s16x8*)(base + aOff[ks]);
    a0 = MFMA16(a, wf0[ks], a0);
    a1 = MFMA16(a, wf1[ks], a1);
  }
}

// ---------------------------------------------------------------------------
// Kernel 1: Wf[o][k] = sum_h h2o[o][h]*l2h[h][k]; bfused[o] = h2o[o].l2h_b + h2o_b[o]
// ---------------------------------------------------------------------------
__global__ __launch_bounds__(128) void wf_kernel(
    const float* __restrict__ h2o, const float* __restrict__ l2h,
    const float* __restrict__ l2hb, const float* __restrict__ h2ob,
    unsigned short* __restrict__ wfo, float* __restrict__ bfo)
{
  const int o = (int)blockIdx.x, k = (int)threadIdx.x;
  float acc = 0.f;
  for (int h = 0; h < 256; ++h) acc = fmaf(h2o[o * 256 + h], l2h[h * 128 + k], acc);
  wfo[o * 128 + k] = f2bf(acc);
  __shared__ float red[128];
  red[k] = h2o[o * 256 + k] * l2hb[k] + h2o[o * 256 + 128 + k] * l2hb[128 + k];
  __syncthreads();
  for (int s = 64; s > 0; s >>= 1) {
    if (k < s) red[k] += red[k + s];
    __syncthreads();
  }
  if (k == 0) bfo[o] = red[0] + h2ob[o];
}

// ---------------------------------------------------------------------------
// Kernel 2: RK4 ODE integration. 64 blocks x 16 rows, 256 thr (4 waves).
// ---------------------------------------------------------------------------
__global__ __launch_bounds__(256) void ode_kernel(
    const float* __restrict__ init, const float* __restrict__ ts,
    const float* __restrict__ w1, const float* __restrict__ b1,
    const float* __restrict__ w2, const float* __restrict__ b2,
    unsigned short* __restrict__ zbuf, float* __restrict__ yfin)
{
  __shared__ __align__(16) unsigned char sY[4096];  // 16 x 128 bf16, swizzled
  __shared__ __align__(16) unsigned char sH[4096];
  const int tid = (int)threadIdx.x;
  const int w = tid >> 6, lane = tid & 63;
  const int l15 = lane & 15, l4 = lane >> 4;
  const int rowbase = (int)blockIdx.x * 16;
  const int colbase = w * 32;

  s16x8 w1f[2][4], w2f[2][4];
#pragma unroll
  for (int tc = 0; tc < 2; ++tc) {
    const int rj = colbase + 16 * tc + l15;
#pragma unroll
    for (int ks = 0; ks < 4; ++ks) {
      const int kb = ks * 32 + l4 * 8;
      s16x8 va, vb;
#pragma unroll
      for (int t = 0; t < 8; ++t) {
        va[t] = (short)f2bf(w1[rj * 128 + kb + t]);
        vb[t] = (short)f2bf(w2[rj * 128 + kb + t]);
      }
      w1f[tc][ks] = va; w2f[tc][ks] = vb;
    }
  }
  float b1v[2], b2v[2];
#pragma unroll
  for (int tc = 0; tc < 2; ++tc) {
    const int cc = colbase + 16 * tc + l15;
    b1v[tc] = b1[cc]; b2v[tc] = b2[cc];
  }

  int aOff[4];
#pragma unroll
  for (int ks = 0; ks < 4; ++ks) aOff[ks] = swz(l15, (ks * 32 + l4 * 8) * 2);
  int cOff[2][4];
#pragma unroll
  for (int tc = 0; tc < 2; ++tc)
#pragma unroll
    for (int r = 0; r < 4; ++r)
      cOff[tc][r] = swz(l4 * 4 + r, (colbase + 16 * tc + l15) * 2);

  float y0[2][4], yac[2][4];
#pragma unroll
  for (int tc = 0; tc < 2; ++tc)
#pragma unroll
    for (int r = 0; r < 4; ++r)
      y0[tc][r] = init[(rowbase + l4 * 4 + r) * 128 + colbase + 16 * tc + l15];

  {
    const int i = tid * 8;
    const int row = i >> 7, col = i & 127;
    union { unsigned short u[8]; s16x8 v; } p;
#pragma unroll
    for (int t = 0; t < 8; ++t) p.u[t] = f2bf(init[(rowbase + row) * 128 + col + t]);
    *(s16x8*)(sY + swz(row, col * 2)) = p.v;
    *(s16x8*)(zbuf + rowbase * 128 + i) = p.v;
  }
  __syncthreads();

  for (int s = 0; s < 127; ++s) {
    const float dt = ts[s + 1] - ts[s];
    const float c16 = dt * (1.f / 6.f), c13 = dt * (1.f / 3.f), ch = dt * 0.5f;
#pragma unroll
    for (int st = 0; st < 4; ++st) {
      f32x4 acc[2];
      const f32x4 fz = {0.f, 0.f, 0.f, 0.f};
      acc[0] = fz; acc[1] = fz;
      gemm_tile(sY, aOff, w1f[0], w1f[1], acc[0], acc[1]);
#pragma unroll
      for (int tc = 0; tc < 2; ++tc)
#pragma unroll
        for (int r = 0; r < 4; ++r) {
          float v = acc[tc][r] + b1v[tc];
          v = v > 0.f ? v : (__expf(v) - 1.f);  // ELU (alpha=1), cheap exp
          *(unsigned short*)(sH + cOff[tc][r]) = f2bf(v);
        }
      __syncthreads();
      f32x4 kc[2];
      kc[0] = fz; kc[1] = fz;
      gemm_tile(sH, aOff, w2f[0], w2f[1], kc[0], kc[1]);
#pragma unroll
      for (int tc = 0; tc < 2; ++tc)
#pragma unroll
        for (int r = 0; r < 4; ++r) {
          const float kv = kc[tc][r] + b2v[tc];
          float yn;
          if (st == 0)      { yac[tc][r] = fmaf(c16, kv, y0[tc][r]);  yn = fmaf(ch, kv, y0[tc][r]); }
          else if (st == 1) { yac[tc][r] = fmaf(c13, kv, yac[tc][r]); yn = fmaf(ch, kv, y0[tc][r]); }
          else if (st == 2) { yac[tc][r] = fmaf(c13, kv, yac[tc][r]); yn = fmaf(dt, kv, y0[tc][r]); }
          else              { y0[tc][r]  = fmaf(c16, kv, yac[tc][r]); yn = y0[tc][r]; }
          *(unsigned short*)(sY + cOff[tc][r]) = f2bf(yn);
        }
      __syncthreads();
    }
    {
      const int i = tid * 8;
      const int row = i >> 7;
      const s16x8 v = *(const s16x8*)(sY + swz(row, (i & 127) * 2));
      *(s16x8*)(zbuf + (long)(s + 1) * 131072 + rowbase * 128 + i) = v;
    }
  }
#pragma unroll
  for (int tc = 0; tc < 2; ++tc)
#pragma unroll
    for (int r = 0; r < 4; ++r)
      yfin[(rowbase + l4 * 4 + r) * 128 + colbase + 16 * tc + l15] = y0[tc][r];
}

// ---------------------------------------------------------------------------
// Kernel 3: XWT[g][t] = Wih[g] . yfin[t] + bih[g] + bhh[g]   (g-major!)
// ---------------------------------------------------------------------------
__global__ __launch_bounds__(256) void xw_kernel(
    const float* __restrict__ yfin, const float* __restrict__ wih,
    const float* __restrict__ bih, const float* __restrict__ bhh,
    float* __restrict__ XWT)
{
  const int t = (int)blockIdx.x, g = (int)threadIdx.x;
  __shared__ __align__(16) float ys[128];
  if (g < 128) ys[g] = yfin[t * 128 + g];
  __syncthreads();
  float a0 = 0.f, a1 = 0.f, a2 = 0.f, a3 = 0.f;
#pragma unroll 8
  for (int k = 0; k < 32; ++k) {
    float4 wv = *(const float4*)(wih + g * 128 + 4 * k);
    float4 yv = *(const float4*)(ys + 4 * k);
    a0 = fmaf(wv.x, yv.x, a0); a1 = fmaf(wv.y, yv.y, a1);
    a2 = fmaf(wv.z, yv.z, a2); a3 = fmaf(wv.w, yv.w, a3);
  }
  XWT[g * 1024 + t] = bih[g] + bhh[g] + ((a0 + a1) + (a2 + a3));
}

// ---------------------------------------------------------------------------
// Fused kernel: blocks 0..2047 = projection xs = zs @ Wf^T + bf
//               block  2048    = the 1024-step LSTM chain (runs concurrently)
// ---------------------------------------------------------------------------
__device__ __forceinline__ void proj_body(
    const unsigned short* __restrict__ zbuf, const unsigned short* __restrict__ wf,
    const float* __restrict__ bfv_, float* __restrict__ xs)
{
  const int tid = (int)threadIdx.x;
  const int w = tid >> 6, lane = tid & 63;
  const int l15 = lane & 15, l4 = lane >> 4;
  const int colbase = w * 32;
  const long rowbase = (long)blockIdx.x * 64;

  s16x8 wff[2][4];
#pragma unroll
  for (int tc = 0; tc < 2; ++tc) {
    const int rj = colbase + 16 * tc + l15;
#pragma unroll
    for (int ks = 0; ks < 4; ++ks)
      wff[tc][ks] = *(const s16x8*)(wf + rj * 128 + ks * 32 + l4 * 8);
  }
  const float bv0 = bfv_[colbase + l15], bv1 = bfv_[colbase + 16 + l15];

  const f32x4 fz = {0.f, 0.f, 0.f, 0.f};
  f32x4 acc[4][2];
#pragma unroll
  for (int rt = 0; rt < 4; ++rt) { acc[rt][0] = fz; acc[rt][1] = fz; }

#pragma unroll
  for (int rt = 0; rt < 4; ++rt) {
    const long rb = rowbase + rt * 16 + l15;
#pragma unroll
    for (int ks = 0; ks < 4; ++ks) {
      const s16x8 a = *(const s16x8*)(zbuf + rb * 128 + ks * 32 + l4 * 8);
      acc[rt][0] = MFMA16(a, wff[0][ks], acc[rt][0]);
      acc[rt][1] = MFMA16(a, wff[1][ks], acc[rt][1]);
    }
  }
#pragma unroll
  for (int rt = 0; rt < 4; ++rt)
#pragma unroll
    for (int r = 0; r < 4; ++r) {
      const long row = rowbase + rt * 16 + l4 * 4 + r;
      xs[row * 128 + colbase + l15]      = acc[rt][0][r] + bv0;
      xs[row * 128 + colbase + 16 + l15] = acc[rt][1][r] + bv1;
    }
}

__device__ __forceinline__ void lstm_body(
    const float* __restrict__ XWT,   // [256][1024]
    const float* __restrict__ whh,   // [256][64]
    float* __restrict__ hsT)         // [64][1024]
{
  const int tid = (int)threadIdx.x;
  const int w = tid >> 6, lane = tid & 63;
  const int jl = lane & 15, q = lane >> 4;
  const int j = w * 16 + jl;       // hidden index this lane carries
  const int G = q * 64 + j;        // gate row (i,f,g,o blocks of 64)

  // Whh row in registers as f32x2 pairs (v_pk_fma_f32 path)
  f32x2 wr[32];
#pragma unroll
  for (int k = 0; k < 16; ++k) {
    float4 v = *(const float4*)(whh + G * 64 + 4 * k);
    wr[2 * k + 0] = (f32x2){v.x, v.y};
    wr[2 * k + 1] = (f32x2){v.z, v.w};
  }
  // unified activation: act = As * rcp(1 + exp(Ss*pre)) + Bs
  const float As = (q == 2) ? 2.f : 1.f;
  const float Ss = (q == 2) ? -2.f : -1.f;
  const float Bs = (q == 2) ? -1.f : 0.f;

  __shared__ __align__(16) float hsb[2][64];   // double-buffered h
  if (tid < 64) hsb[0][tid] = 0.f;
  float c = 0.f;
  float hh[16];
  const float* xwp = XWT + G * 1024;
  // first XW chunk (t=0..15) into registers
  float4 xb0 = *(const float4*)(xwp + 0);
  float4 xb1 = *(const float4*)(xwp + 4);
  float4 xb2 = *(const float4*)(xwp + 8);
  float4 xb3 = *(const float4*)(xwp + 12);
  __syncthreads();

  for (int tc = 0; tc < 64; ++tc) {
    const int t0 = tc * 16;
    // prefetch next chunk (valid dummy addr on last iter)
    const float* np = xwp + ((tc < 63) ? (t0 + 16) : 0);
    float4 nb0 = *(const float4*)(np + 0);
    float4 nb1 = *(const float4*)(np + 4);
    float4 nb2 = *(const float4*)(np + 8);
    float4 nb3 = *(const float4*)(np + 12);

#pragma unroll
    for (int ti = 0; ti < 16; ++ti) {
      const int par = ti & 1;  // read hsb[par], write hsb[par^1]
      const float4 xbv = ((ti >> 2) == 0) ? xb0 : ((ti >> 2) == 1) ? xb1
                       : ((ti >> 2) == 2) ? xb2 : xb3;
      const float xw = ((ti & 3) == 0) ? xbv.x : ((ti & 3) == 1) ? xbv.y
                     : ((ti & 3) == 2) ? xbv.z : xbv.w;
      const float* hp = hsb[par];
      f32x2 a0 = {0.f, 0.f}, a1 = {0.f, 0.f}, a2 = {0.f, 0.f}, a3 = {0.f, 0.f};
#pragma unroll
      for (int k = 0; k < 8; ++k) {
        float4 h0 = *(const float4*)(hp + 8 * k);
        float4 h1 = *(const float4*)(hp + 8 * k + 4);
        a0 = wr[4 * k + 0] * (f32x2){h0.x, h0.y} + a0;
        a1 = wr[4 * k + 1] * (f32x2){h0.z, h0.w} + a1;
        a2 = wr[4 * k + 2] * (f32x2){h1.x, h1.y} + a2;
        a3 = wr[4 * k + 3] * (f32x2){h1.z, h1.w} + a3;
      }
      const float pre = xw + ((a0.x + a0.y) + (a1.x + a1.y))
                           + ((a2.x + a2.y) + (a3.x + a3.y));
      const float e = __expf(Ss * pre);
      const float act = fmaf(As, __builtin_amdgcn_rcpf(1.f + e), Bs);
      // gather the 4 gate values for hidden j (in-wave, no barrier)
      const float v16 = __shfl_xor(act, 16);
      const float v32 = __shfl_xor(act, 32);
      const float v48 = __shfl_xor(act, 48);
      const bool b1 = (q & 1), b2 = (q & 2);
      const float si = b2 ? (b1 ? v48 : v32) : (b1 ? v16 : act);
      const float sf = b2 ? (b1 ? v32 : v48) : (b1 ? act : v16);
      const float tg = b2 ? (b1 ? v16 : act) : (b1 ? v48 : v32);
      const float so = b2 ? (b1 ? act : v16) : (b1 ? v32 : v48);
      c = fmaf(sf, c, si * tg);  // replicated identically in all 4 lane groups
      const float th = fmaf(2.f, __builtin_amdgcn_rcpf(1.f + __expf(-2.f * c)), -1.f);
      const float h = so * th;
      hh[ti] = h;
      if (q == 0) hsb[par ^ 1][j] = h;
      __syncthreads();
    }
    // burst h history to global (transposed [j][t]), swap XW chunk regs
    if (q == 0) {
      float* o = hsT + j * 1024 + t0;
      *(float4*)(o + 0)  = (float4){hh[0], hh[1], hh[2], hh[3]};
      *(float4*)(o + 4)  = (float4){hh[4], hh[5], hh[6], hh[7]};
      *(float4*)(o + 8)  = (float4){hh[8], hh[9], hh[10], hh[11]};
      *(float4*)(o + 12) = (float4){hh[12], hh[13], hh[14], hh[15]};
    }
    xb0 = nb0; xb1 = nb1; xb2 = nb2; xb3 = nb3;
  }
}

__global__ __launch_bounds__(256) void proj_lstm_kernel(
    const unsigned short* __restrict__ zbuf, const unsigned short* __restrict__ wf,
    const float* __restrict__ bfv_, float* __restrict__ xs,
    const float* __restrict__ XWT, const float* __restrict__ whh,
    float* __restrict__ hsT)
{
  if (blockIdx.x < 2048) proj_body(zbuf, wf, bfv_, xs);
  else                   lstm_body(XWT, whh, hsT);
}

// ---------------------------------------------------------------------------
// Kernel 5: lstm_out[t][n] = fc2_w[n] . h_t + fc2_b[n]  (reads hsT [64][1024])
// ---------------------------------------------------------------------------
__global__ __launch_bounds__(256) void fc2_kernel(
    const float* __restrict__ hsT, const float* __restrict__ fw,
    const float* __restrict__ fb, float* __restrict__ lout)
{
  const int idx = (int)blockIdx.x * 256 + (int)threadIdx.x;  // 0..2047
  const int n = idx >> 10, t = idx & 1023;
  float acc = fb[n];
#pragma unroll 8
  for (int j = 0; j < 64; ++j) acc = fmaf(fw[n * 64 + j], hsT[j * 1024 + t], acc);
  lout[t * 2 + n] = acc;
}

// ---------------------------------------------------------------------------
extern "C" void kernel_launch(void* const* d_in, const int* in_sizes, int n_in,
                              void* d_out, int out_size, void* d_ws, size_t ws_size,
                              hipStream_t stream) {
  const float* init  = (const float*)d_in[0];
  const float* ts    = (const float*)d_in[1];
  const float* ode_w1 = (const float*)d_in[2];
  const float* ode_b1 = (const float*)d_in[3];
  const float* ode_w2 = (const float*)d_in[4];
  const float* ode_b2 = (const float*)d_in[5];
  const float* l2h_w = (const float*)d_in[6];
  const float* l2h_b = (const float*)d_in[7];
  const float* h2o_w = (const float*)d_in[8];
  const float* h2o_b = (const float*)d_in[9];
  const float* wih   = (const float*)d_in[10];
  const float* whh   = (const float*)d_in[11];
  const float* bih   = (const float*)d_in[12];
  const float* bhh   = (const float*)d_in[13];
  const float* fc2w  = (const float*)d_in[14];
  const float* fc2b  = (const float*)d_in[15];

  char* ws = (char*)d_ws;
  unsigned short* zbuf  = (unsigned short*)(ws);               // 33,554,432 B
  float* yfin           = (float*)(ws + 33554432);             //    524,288 B
  float* XWT            = (float*)(ws + 34078720);             //  1,048,576 B
  float* hsT            = (float*)(ws + 35127296);             //    262,144 B
  unsigned short* wfbuf = (unsigned short*)(ws + 35389440);    //     32,768 B
  float* bfused         = (float*)(ws + 35422208);             //        512 B

  float* xs   = (float*)d_out;
  float* lout = xs + 16777216;

  wf_kernel<<<128, 128, 0, stream>>>(h2o_w, l2h_w, l2h_b, h2o_b, wfbuf, bfused);
  ode_kernel<<<64, 256, 0, stream>>>(init, ts, ode_w1, ode_b1, ode_w2, ode_b2, zbuf, yfin);
  xw_kernel<<<1024, 256, 0, stream>>>(yfin, wih, bih, bhh, XWT);
  proj_lstm_kernel<<<2049, 256, 0, stream>>>(zbuf, wfbuf, bfused, xs, XWT, whh, hsT);
  fc2_kernel<<<8, 256, 0, stream>>>(hsT, fc2w, fc2b, lout);
}

// Round 5
// 812.088 us; speedup vs baseline: 1.4629x; 1.0019x over previous
//
#include <hip/hip_runtime.h>

// B=1024, T=128, LAT=128, HODE=128, HID=256, OUT=128, NC=2, H=64.
// d_out = xs [128,1024,128] f32 ++ lstm_out [1024,2] f32.
//
// Structure: wf (fuse l2h*h2o) ; ode (per-block RK4 chains) ; xw (Wih.yfin, transposed out)
//            fused(proj blocks 0..2047 || lstm chain block 2048) ; fc2.
//
// R3 change: inner-loop __syncthreads() -> lgkmcnt-only barrier (no vmcnt drain),
// keeping global prefetch loads / export stores in flight across barriers.

typedef short s16x8 __attribute__((ext_vector_type(8)));
typedef float f32x4 __attribute__((ext_vector_type(4)));
typedef float f32x2 __attribute__((ext_vector_type(2)));

#define MFMA16(a, b, c) __builtin_amdgcn_mfma_f32_16x16x32_bf16((a), (b), (c), 0, 0, 0)

// Barrier that waits only on LDS ops (lgkmcnt), NOT vmcnt -- __syncthreads()
// would drain vmcnt(0) and expose global load/store latency on the chain.
__device__ __forceinline__ void lds_barrier() {
  asm volatile("s_waitcnt lgkmcnt(0)\n\ts_barrier" ::: "memory");
}

__device__ __forceinline__ unsigned short f2bf(float x) {
  union { float f; unsigned u; } v; v.f = x;
  return (unsigned short)((v.u + 0x7FFFu + ((v.u >> 16) & 1u)) >> 16);  // RNE
}

// XOR-swizzled LDS byte offset for a [rows][128] bf16 tile (row stride 256B).
__device__ __forceinline__ int swz(int row, int col2) {
  return row * 256 + (col2 ^ ((row & 7) << 4));
}

__device__ __forceinline__ void gemm_tile(const unsigned char* base,
                                          const int* aOff,
                                          const s16x8* wf0, const s16x8* wf1,
                                          f32x4& a0, f32x4& a1) {
#pragma unroll
  for (int ks = 0; ks < 4; ++ks) {
    s16x8 a = *(const s16x8*)(base + aOff[ks]);
    a0 = MFMA16(a, wf0[ks], a0);
    a1 = MFMA16(a, wf1[ks], a1);
  }
}

// ---------------------------------------------------------------------------
// Kernel 1: Wf[o][k] = sum_h h2o[o][h]*l2h[h][k]; bfused[o] = h2o[o].l2h_b + h2o_b[o]
// ---------------------------------------------------------------------------
__global__ __launch_bounds__(128) void wf_kernel(
    const float* __restrict__ h2o, const float* __restrict__ l2h,
    const float* __restrict__ l2hb, const float* __restrict__ h2ob,
    unsigned short* __restrict__ wfo, float* __restrict__ bfo)
{
  const int o = (int)blockIdx.x, k = (int)threadIdx.x;
  float acc = 0.f;
  for (int h = 0; h < 256; ++h) acc = fmaf(h2o[o * 256 + h], l2h[h * 128 + k], acc);
  wfo[o * 128 + k] = f2bf(acc);
  __shared__ float red[128];
  red[k] = h2o[o * 256 + k] * l2hb[k] + h2o[o * 256 + 128 + k] * l2hb[128 + k];
  __syncthreads();
  for (int s = 64; s > 0; s >>= 1) {
    if (k < s) red[k] += red[k + s];
    __syncthreads();
  }
  if (k == 0) bfo[o] = red[0] + h2ob[o];
}

// ---------------------------------------------------------------------------
// Kernel 2: RK4 ODE integration. 64 blocks x 16 rows, 256 thr (4 waves).
// ---------------------------------------------------------------------------
__global__ __launch_bounds__(256) void ode_kernel(
    const float* __restrict__ init, const float* __restrict__ ts,
    const float* __restrict__ w1, const float* __restrict__ b1,
    const float* __restrict__ w2, const float* __restrict__ b2,
    unsigned short* __restrict__ zbuf, float* __restrict__ yfin)
{
  __shared__ __align__(16) unsigned char sY[4096];  // 16 x 128 bf16, swizzled
  __shared__ __align__(16) unsigned char sH[4096];
  const int tid = (int)threadIdx.x;
  const int w = tid >> 6, lane = tid & 63;
  const int l15 = lane & 15, l4 = lane >> 4;
  const int rowbase = (int)blockIdx.x * 16;
  const int colbase = w * 32;

  s16x8 w1f[2][4], w2f[2][4];
#pragma unroll
  for (int tc = 0; tc < 2; ++tc) {
    const int rj = colbase + 16 * tc + l15;
#pragma unroll
    for (int ks = 0; ks < 4; ++ks) {
      const int kb = ks * 32 + l4 * 8;
      s16x8 va, vb;
#pragma unroll
      for (int t = 0; t < 8; ++t) {
        va[t] = (short)f2bf(w1[rj * 128 + kb + t]);
        vb[t] = (short)f2bf(w2[rj * 128 + kb + t]);
      }
      w1f[tc][ks] = va; w2f[tc][ks] = vb;
    }
  }
  float b1v[2], b2v[2];
#pragma unroll
  for (int tc = 0; tc < 2; ++tc) {
    const int cc = colbase + 16 * tc + l15;
    b1v[tc] = b1[cc]; b2v[tc] = b2[cc];
  }

  int aOff[4];
#pragma unroll
  for (int ks = 0; ks < 4; ++ks) aOff[ks] = swz(l15, (ks * 32 + l4 * 8) * 2);
  int cOff[2][4];
#pragma unroll
  for (int tc = 0; tc < 2; ++tc)
#pragma unroll
    for (int r = 0; r < 4; ++r)
      cOff[tc][r] = swz(l4 * 4 + r, (colbase + 16 * tc + l15) * 2);

  float y0[2][4], yac[2][4];
#pragma unroll
  for (int tc = 0; tc < 2; ++tc)
#pragma unroll
    for (int r = 0; r < 4; ++r)
      y0[tc][r] = init[(rowbase + l4 * 4 + r) * 128 + colbase + 16 * tc + l15];

  {
    const int i = tid * 8;
    const int row = i >> 7, col = i & 127;
    union { unsigned short u[8]; s16x8 v; } p;
#pragma unroll
    for (int t = 0; t < 8; ++t) p.u[t] = f2bf(init[(rowbase + row) * 128 + col + t]);
    *(s16x8*)(sY + swz(row, col * 2)) = p.v;
    *(s16x8*)(zbuf + rowbase * 128 + i) = p.v;
  }
  __syncthreads();

  for (int s = 0; s < 127; ++s) {
    const float dt = ts[s + 1] - ts[s];
    const float c16 = dt * (1.f / 6.f), c13 = dt * (1.f / 3.f), ch = dt * 0.5f;
#pragma unroll
    for (int st = 0; st < 4; ++st) {
      f32x4 acc[2];
      const f32x4 fz = {0.f, 0.f, 0.f, 0.f};
      acc[0] = fz; acc[1] = fz;
      gemm_tile(sY, aOff, w1f[0], w1f[1], acc[0], acc[1]);
#pragma unroll
      for (int tc = 0; tc < 2; ++tc)
#pragma unroll
        for (int r = 0; r < 4; ++r) {
          float v = acc[tc][r] + b1v[tc];
          v = v > 0.f ? v : (__expf(v) - 1.f);  // ELU (alpha=1), cheap exp
          *(unsigned short*)(sH + cOff[tc][r]) = f2bf(v);
        }
      lds_barrier();
      f32x4 kc[2];
      kc[0] = fz; kc[1] = fz;
      gemm_tile(sH, aOff, w2f[0], w2f[1], kc[0], kc[1]);
#pragma unroll
      for (int tc = 0; tc < 2; ++tc)
#pragma unroll
        for (int r = 0; r < 4; ++r) {
          const float kv = kc[tc][r] + b2v[tc];
          float yn;
          if (st == 0)      { yac[tc][r] = fmaf(c16, kv, y0[tc][r]);  yn = fmaf(ch, kv, y0[tc][r]); }
          else if (st == 1) { yac[tc][r] = fmaf(c13, kv, yac[tc][r]); yn = fmaf(ch, kv, y0[tc][r]); }
          else if (st == 2) { yac[tc][r] = fmaf(c13, kv, yac[tc][r]); yn = fmaf(dt, kv, y0[tc][r]); }
          else              { y0[tc][r]  = fmaf(c16, kv, yac[tc][r]); yn = y0[tc][r]; }
          *(unsigned short*)(sY + cOff[tc][r]) = f2bf(yn);
        }
      lds_barrier();
    }
    {
      const int i = tid * 8;
      const int row = i >> 7;
      const s16x8 v = *(const s16x8*)(sY + swz(row, (i & 127) * 2));
      *(s16x8*)(zbuf + (long)(s + 1) * 131072 + rowbase * 128 + i) = v;
    }
  }
#pragma unroll
  for (int tc = 0; tc < 2; ++tc)
#pragma unroll
    for (int r = 0; r < 4; ++r)
      yfin[(rowbase + l4 * 4 + r) * 128 + colbase + 16 * tc + l15] = y0[tc][r];
}

// ---------------------------------------------------------------------------
// Kernel 3: XWT[g][t] = Wih[g] . yfin[t] + bih[g] + bhh[g]   (g-major!)
// ---------------------------------------------------------------------------
__global__ __launch_bounds__(256) void xw_kernel(
    const float* __restrict__ yfin, const float* __restrict__ wih,
    const float* __restrict__ bih, const float* __restrict__ bhh,
    float* __restrict__ XWT)
{
  const int t = (int)blockIdx.x, g = (int)threadIdx.x;
  __shared__ __align__(16) float ys[128];
  if (g < 128) ys[g] = yfin[t * 128 + g];
  __syncthreads();
  float a0 = 0.f, a1 = 0.f, a2 = 0.f, a3 = 0.f;
#pragma unroll 8
  for (int k = 0; k < 32; ++k) {
    float4 wv = *(const float4*)(wih + g * 128 + 4 * k);
    float4 yv = *(const float4*)(ys + 4 * k);
    a0 = fmaf(wv.x, yv.x, a0); a1 = fmaf(wv.y, yv.y, a1);
    a2 = fmaf(wv.z, yv.z, a2); a3 = fmaf(wv.w, yv.w, a3);
  }
  XWT[g * 1024 + t] = bih[g] + bhh[g] + ((a0 + a1) + (a2 + a3));
}

// ---------------------------------------------------------------------------
// Fused kernel: blocks 0..2047 = projection xs = zs @ Wf^T + bf
//               block  2048    = the 1024-step LSTM chain (runs concurrently)
// ---------------------------------------------------------------------------
__device__ __forceinline__ void proj_body(
    const unsigned short* __restrict__ zbuf, const unsigned short* __restrict__ wf,
    const float* __restrict__ bfv_, float* __restrict__ xs)
{
  const int tid = (int)threadIdx.x;
  const int w = tid >> 6, lane = tid & 63;
  const int l15 = lane & 15, l4 = lane >> 4;
  const int colbase = w * 32;
  const long rowbase = (long)blockIdx.x * 64;

  s16x8 wff[2][4];
#pragma unroll
  for (int tc = 0; tc < 2; ++tc) {
    const int rj = colbase + 16 * tc + l15;
#pragma unroll
    for (int ks = 0; ks < 4; ++ks)
      wff[tc][ks] = *(const s16x8*)(wf + rj * 128 + ks * 32 + l4 * 8);
  }
  const float bv0 = bfv_[colbase + l15], bv1 = bfv_[colbase + 16 + l15];

  const f32x4 fz = {0.f, 0.f, 0.f, 0.f};
  f32x4 acc[4][2];
#pragma unroll
  for (int rt = 0; rt < 4; ++rt) { acc[rt][0] = fz; acc[rt][1] = fz; }

#pragma unroll
  for (int rt = 0; rt < 4; ++rt) {
    const long rb = rowbase + rt * 16 + l15;
#pragma unroll
    for (int ks = 0; ks < 4; ++ks) {
      const s16x8 a = *(const s16x8*)(zbuf + rb * 128 + ks * 32 + l4 * 8);
      acc[rt][0] = MFMA16(a, wff[0][ks], acc[rt][0]);
      acc[rt][1] = MFMA16(a, wff[1][ks], acc[rt][1]);
    }
  }
#pragma unroll
  for (int rt = 0; rt < 4; ++rt)
#pragma unroll
    for (int r = 0; r < 4; ++r) {
      const long row = rowbase + rt * 16 + l4 * 4 + r;
      xs[row * 128 + colbase + l15]      = acc[rt][0][r] + bv0;
      xs[row * 128 + colbase + 16 + l15] = acc[rt][1][r] + bv1;
    }
}

__device__ __forceinline__ void lstm_body(
    const float* __restrict__ XWT,   // [256][1024]
    const float* __restrict__ whh,   // [256][64]
    float* __restrict__ hsT)         // [64][1024]
{
  const int tid = (int)threadIdx.x;
  const int w = tid >> 6, lane = tid & 63;
  const int jl = lane & 15, q = lane >> 4;
  const int j = w * 16 + jl;       // hidden index this lane carries
  const int G = q * 64 + j;        // gate row (i,f,g,o blocks of 64)

  // Whh row in registers as f32x2 pairs (v_pk_fma_f32 path)
  f32x2 wr[32];
#pragma unroll
  for (int k = 0; k < 16; ++k) {
    float4 v = *(const float4*)(whh + G * 64 + 4 * k);
    wr[2 * k + 0] = (f32x2){v.x, v.y};
    wr[2 * k + 1] = (f32x2){v.z, v.w};
  }
  // unified activation: act = As * rcp(1 + exp(Ss*pre)) + Bs
  const float As = (q == 2) ? 2.f : 1.f;
  const float Ss = (q == 2) ? -2.f : -1.f;
  const float Bs = (q == 2) ? -1.f : 0.f;

  __shared__ __align__(16) float hsb[2][64];   // double-buffered h
  if (tid < 64) hsb[0][tid] = 0.f;
  float c = 0.f;
  float hh[16];
  const float* xwp = XWT + G * 1024;
  // first XW chunk (t=0..15) into registers
  float4 xb0 = *(const float4*)(xwp + 0);
  float4 xb1 = *(const float4*)(xwp + 4);
  float4 xb2 = *(const float4*)(xwp + 8);
  float4 xb3 = *(const float4*)(xwp + 12);
  __syncthreads();

  for (int tc = 0; tc < 64; ++tc) {
    const int t0 = tc * 16;
    // prefetch next chunk (valid dummy addr on last iter); stays in flight
    // across the lgkmcnt-only barriers below.
    const float* np = xwp + ((tc < 63) ? (t0 + 16) : 0);
    float4 nb0 = *(const float4*)(np + 0);
    float4 nb1 = *(const float4*)(np + 4);
    float4 nb2 = *(const float4*)(np + 8);
    float4 nb3 = *(const float4*)(np + 12);

#pragma unroll
    for (int ti = 0; ti < 16; ++ti) {
      const int par = ti & 1;  // read hsb[par], write hsb[par^1]
      const float4 xbv = ((ti >> 2) == 0) ? xb0 : ((ti >> 2) == 1) ? xb1
                       : ((ti >> 2) == 2) ? xb2 : xb3;
      const float xw = ((ti & 3) == 0) ? xbv.x : ((ti & 3) == 1) ? xbv.y
                     : ((ti & 3) == 2) ? xbv.z : xbv.w;
      const float* hp = hsb[par];
      f32x2 a0 = {0.f, 0.f}, a1 = {0.f, 0.f}, a2 = {0.f, 0.f}, a3 = {0.f, 0.f};
#pragma unroll
      for (int k = 0; k < 8; ++k) {
        float4 h0 = *(const float4*)(hp + 8 * k);
        float4 h1 = *(const float4*)(hp + 8 * k + 4);
        a0 = wr[4 * k + 0] * (f32x2){h0.x, h0.y} + a0;
        a1 = wr[4 * k + 1] * (f32x2){h0.z, h0.w} + a1;
        a2 = wr[4 * k + 2] * (f32x2){h1.x, h1.y} + a2;
        a3 = wr[4 * k + 3] * (f32x2){h1.z, h1.w} + a3;
      }
      const float pre = xw + ((a0.x + a0.y) + (a1.x + a1.y))
                           + ((a2.x + a2.y) + (a3.x + a3.y));
      const float e = __expf(Ss * pre);
      const float act = fmaf(As, __builtin_amdgcn_rcpf(1.f + e), Bs);
      // gather the 4 gate values for hidden j (in-wave, no barrier)
      const float v16 = __shfl_xor(act, 16);
      const float v32 = __shfl_xor(act, 32);
      const float v48 = __shfl_xor(act, 48);
      const bool b1 = (q & 1), b2 = (q & 2);
      const float si = b2 ? (b1 ? v48 : v32) : (b1 ? v16 : act);
      const float sf = b2 ? (b1 ? v32 : v48) : (b1 ? act : v16);
      const float tg = b2 ? (b1 ? v16 : act) : (b1 ? v48 : v32);
      const float so = b2 ? (b1 ? act : v16) : (b1 ? v32 : v48);
      c = fmaf(sf, c, si * tg);  // replicated identically in all 4 lane groups
      const float th = fmaf(2.f, __builtin_amdgcn_rcpf(1.f + __expf(-2.f * c)), -1.f);
      const float h = so * th;
      hh[ti] = h;
      if (q == 0) hsb[par ^ 1][j] = h;
      lds_barrier();   // lgkmcnt-only: keeps XW prefetch + hsT stores in flight
    }
    // burst h history to global (transposed [j][t]), swap XW chunk regs
    if (q == 0) {
      float* o = hsT + j * 1024 + t0;
      *(float4*)(o + 0)  = (float4){hh[0], hh[1], hh[2], hh[3]};
      *(float4*)(o + 4)  = (float4){hh[4], hh[5], hh[6], hh[7]};
      *(float4*)(o + 8)  = (float4){hh[8], hh[9], hh[10], hh[11]};
      *(float4*)(o + 12) = (float4){hh[12], hh[13], hh[14], hh[15]};
    }
    xb0 = nb0; xb1 = nb1; xb2 = nb2; xb3 = nb3;
  }
}

__global__ __launch_bounds__(256) void proj_lstm_kernel(
    const unsigned short* __restrict__ zbuf, const unsigned short* __restrict__ wf,
    const float* __restrict__ bfv_, float* __restrict__ xs,
    const float* __restrict__ XWT, const float* __restrict__ whh,
    float* __restrict__ hsT)
{
  if (blockIdx.x < 2048) proj_body(zbuf, wf, bfv_, xs);
  else                   lstm_body(XWT, whh, hsT);
}

// ---------------------------------------------------------------------------
// Kernel 5: lstm_out[t][n] = fc2_w[n] . h_t + fc2_b[n]  (reads hsT [64][1024])
// ---------------------------------------------------------------------------
__global__ __launch_bounds__(256) void fc2_kernel(
    const float* __restrict__ hsT, const float* __restrict__ fw,
    const float* __restrict__ fb, float* __restrict__ lout)
{
  const int idx = (int)blockIdx.x * 256 + (int)threadIdx.x;  // 0..2047
  const int n = idx >> 10, t = idx & 1023;
  float acc = fb[n];
#pragma unroll 8
  for (int j = 0; j < 64; ++j) acc = fmaf(fw[n * 64 + j], hsT[j * 1024 + t], acc);
  lout[t * 2 + n] = acc;
}

// ---------------------------------------------------------------------------
extern "C" void kernel_launch(void* const* d_in, const int* in_sizes, int n_in,
                              void* d_out, int out_size, void* d_ws, size_t ws_size,
                              hipStream_t stream) {
  const float* init  = (const float*)d_in[0];
  const float* ts    = (const float*)d_in[1];
  const float* ode_w1 = (const float*)d_in[2];
  const float* ode_b1 = (const float*)d_in[3];
  const float* ode_w2 = (const float*)d_in[4];
  const float* ode_b2 = (const float*)d_in[5];
  const float* l2h_w = (const float*)d_in[6];
  const float* l2h_b = (const float*)d_in[7];
  const float* h2o_w = (const float*)d_in[8];
  const float* h2o_b = (const float*)d_in[9];
  const float* wih   = (const float*)d_in[10];
  const float* whh   = (const float*)d_in[11];
  const float* bih   = (const float*)d_in[12];
  const float* bhh   = (const float*)d_in[13];
  const float* fc2w  = (const float*)d_in[14];
  const float* fc2b  = (const float*)d_in[15];

  char* ws = (char*)d_ws;
  unsigned short* zbuf  = (unsigned short*)(ws);               // 33,554,432 B
  float* yfin           = (float*)(ws + 33554432);             //    524,288 B
  float* XWT            = (float*)(ws + 34078720);             //  1,048,576 B
  float* hsT            = (float*)(ws + 35127296);             //    262,144 B
  unsigned short* wfbuf = (unsigned short*)(ws + 35389440);    //     32,768 B
  float* bfused         = (float*)(ws + 35422208);             //        512 B

  float* xs   = (float*)d_out;
  float* lout = xs + 16777216;

  wf_kernel<<<128, 128, 0, stream>>>(h2o_w, l2h_w, l2h_b, h2o_b, wfbuf, bfused);
  ode_kernel<<<64, 256, 0, stream>>>(init, ts, ode_w1, ode_b1, ode_w2, ode_b2, zbuf, yfin);
  xw_kernel<<<1024, 256, 0, stream>>>(yfin, wih, bih, bhh, XWT);
  proj_lstm_kernel<<<2049, 256, 0, stream>>>(zbuf, wfbuf, bfused, xs, XWT, whh, hsT);
  fc2_kernel<<<8, 256, 0, stream>>>(hsT, fc2w, fc2b, lout);
}